// Round 1
// baseline (301.959 us; speedup 1.0000x reference)
//
#include <hip/hip_runtime.h>

typedef unsigned short u16;
typedef unsigned int   u32;
typedef __attribute__((ext_vector_type(8))) short bf16x8;  // 8 bf16 (4 VGPRs)
typedef __attribute__((ext_vector_type(4))) float f32x4;   // MFMA acc

#define NEL (8192*128)

__device__ __forceinline__ u16 f2bf(float f){
  u32 u = __builtin_bit_cast(u32, f);
  u = (u + 0x7FFFu + ((u >> 16) & 1u)) >> 16;  // RNE, no NaN inputs here
  return (u16)u;
}

// ---------------- degrees: 4 atomic streams, f32 adds of 1.0 (exact) ----------------
__global__ __launch_bounds__(256) void deg_kernel(const int* __restrict__ eab,
                                                  const int* __restrict__ eba,
                                                  float* __restrict__ deg){
  int e = blockIdx.x*256 + threadIdx.x;
  if (e < 65536){
    atomicAdd(&deg[eab[e]],              1.f);  // edge_ab src -> deg_a
    atomicAdd(&deg[4096 + eab[65536+e]], 1.f);  // edge_ab dst -> deg_b
    atomicAdd(&deg[4096 + eba[e]],       1.f);  // edge_ba src -> deg_b
    atomicAdd(&deg[eba[65536+e]],        1.f);  // edge_ba dst -> deg_a
  }
}

// ---------------- LN(x) then x@{Wq,Wk,Wv}+b -> bf16 Q,K,V  (16 rows/block) ----------------
__global__ __launch_bounds__(256) void ln_qkv_kernel(
    const float* __restrict__ xa, const float* __restrict__ xb,
    const float* __restrict__ g, const float* __restrict__ b,
    const float* __restrict__ Wq, const float* __restrict__ bq,
    const float* __restrict__ Wk, const float* __restrict__ bk,
    const float* __restrict__ Wv, const float* __restrict__ bv,
    u16* __restrict__ Qb, u16* __restrict__ Kb, u16* __restrict__ Vb)
{
  __shared__ float xs[16][129];
  const int t = threadIdx.x;
  const int row0 = blockIdx.x*16;
  const float* x = (row0 < 4096) ? (xa + row0*128) : (xb + (row0-4096)*128);
  #pragma unroll
  for (int i=0;i<2;i++){
    int id = t + i*256; int r = id>>5, c4 = (id&31)*4;
    float4 v = *(const float4*)(x + r*128 + c4);
    xs[r][c4]=v.x; xs[r][c4+1]=v.y; xs[r][c4+2]=v.z; xs[r][c4+3]=v.w;
  }
  __syncthreads();
  { // LN: 16 threads per row, stats via shfl within 16-lane group
    int r = t>>4, c0 = t&15;
    float s=0.f, s2=0.f;
    #pragma unroll
    for (int j=0;j<8;j++){ float v = xs[r][c0+j*16]; s+=v; s2+=v*v; }
    #pragma unroll
    for (int m=1;m<16;m<<=1){ s += __shfl_xor(s,m); s2 += __shfl_xor(s2,m); }
    float mean = s*0.0078125f;
    float var  = s2*0.0078125f - mean*mean;
    float rstd = rsqrtf(var + 1e-5f);
    #pragma unroll
    for (int j=0;j<8;j++){ int c=c0+j*16; xs[r][c] = (xs[r][c]-mean)*rstd*g[c] + b[c]; }
  }
  __syncthreads();
  const int col = t&127, rg = t>>7;
  float aq[8], ak[8], av[8];
  #pragma unroll
  for (int r=0;r<8;r++){ aq[r]=0.f; ak[r]=0.f; av[r]=0.f; }
  #pragma unroll 8
  for (int k=0;k<128;k++){
    float wq = Wq[k*128+col], wk = Wk[k*128+col], wv = Wv[k*128+col];
    #pragma unroll
    for (int r=0;r<8;r++){
      float xv = xs[r*2+rg][k];           // LDS broadcast within wave
      aq[r] = fmaf(xv,wq,aq[r]); ak[r] = fmaf(xv,wk,ak[r]); av[r] = fmaf(xv,wv,av[r]);
    }
  }
  float bqv=bq[col], bkv=bk[col], bvv=bv[col];
  #pragma unroll
  for (int r=0;r<8;r++){
    int row = row0 + r*2 + rg;
    Qb[row*128+col] = f2bf(aq[r]+bqv);
    Kb[row*128+col] = f2bf(ak[r]+bkv);
    Vb[row*128+col] = f2bf(av[r]+bvv);
  }
}

// ---------------- V [8192][128] -> V^T [128][8192] (bf16) ----------------
__global__ __launch_bounds__(256) void transpose_kernel(const u16* __restrict__ Vb,
                                                        u16* __restrict__ VT){
  __shared__ __align__(16) u16 tile[64][80];   // stride 160B: 16B-aligned rows
  const int r0 = blockIdx.x*64, c0 = blockIdx.y*64;
  const int t = threadIdx.x;
  #pragma unroll
  for (int i=0;i<2;i++){
    int id = t + i*256; int r = id>>3, cc = id&7;
    *(bf16x8*)&tile[r][cc*8] = *(const bf16x8*)(Vb + (r0+r)*128 + c0 + cc*8);
  }
  __syncthreads();
  #pragma unroll
  for (int i=0;i<2;i++){
    int id = t + i*256; int c = id>>3, rr = (id&7)*8;
    bf16x8 v;
    #pragma unroll
    for (int j=0;j<8;j++) v[j] = (short)tile[rr+j][c];
    *(bf16x8*)(VT + (c0+c)*8192 + r0 + rr) = v;
  }
}

// ---------------- flash attention, both directions ----------------
// block = 256 thr = 4 waves = 4 heads, 16 queries/block, KBLK=64.
// S^T = K.Q^T  (C-frag: col=q=lane&15 -> per-lane softmax rows)
// out^T = V^T.P^T accumulated in f32; P bounced via per-wave LDS (bf16).
// K/VT LDS tiles chunk-XOR-swizzled: chunk sc = cc ^ (row&7), chunk=16B.
__global__ __launch_bounds__(256) void attn_kernel(
    const u16* __restrict__ Qb, const u16* __restrict__ Kb,
    const u16* __restrict__ VT, const float* __restrict__ rel_ab,
    const float* __restrict__ rel_ba, float* __restrict__ attnraw)
{
  __shared__ __align__(16) u16 Klds [1024*8];  // 64 keys x 16 chunks
  __shared__ __align__(16) u16 VTlds[1024*8];  // 128 d   x  8 chunks
  __shared__ __align__(16) u16 Plds [4096];    // 4 waves x 16 q x 64 keys
  const int t = threadIdx.x, wave = t>>6, lane = t&63;
  const int lq = lane&15, lg = lane>>4;
  const int dir = blockIdx.y;
  const int qrow0 = blockIdx.x*16 + (dir ? 4096 : 0);
  const int kvb0  = dir ? 0 : 4096;
  const float rel = dir ? rel_ab[0] : rel_ba[0];
  const int h = wave;
  // Q B-frag: B[k=d][col=q]: lane -> col=lq, k=8*lg+e
  bf16x8 qf = *(const bf16x8*)(Qb + (qrow0+lq)*128 + h*32 + lg*8);
  f32x4 acc0 = {0.f,0.f,0.f,0.f}, acc1 = {0.f,0.f,0.f,0.f};
  float mrow = -1e30f, lrow = 0.f;
  const float scale = 0.17677669529663687f;   // 1/sqrt(32)
  const f32x4 zero = {0.f,0.f,0.f,0.f};
  for (int kt=0; kt<64; ++kt){
    const int kvb = kvb0 + kt*64;
    __syncthreads();
    #pragma unroll
    for (int i=0;i<4;i++){                    // K tile: 1024 16B chunks
      int L = i*256 + t;
      int row = L>>4, sc = L&15, cc = sc ^ (row&7);
      *(bf16x8*)&Klds[L*8] = *(const bf16x8*)(Kb + (kvb+row)*128 + cc*8);
    }
    #pragma unroll
    for (int i=0;i<4;i++){                    // V^T tile: 1024 16B chunks
      int L = i*256 + t;
      int row = L>>3, sc = L&7, cc = sc ^ (row&7);
      *(bf16x8*)&VTlds[L*8] = *(const bf16x8*)(VT + row*8192 + kvb + cc*8);
    }
    __syncthreads();
    // S^T: 4 key-subtiles; A=K (row=key=lq, k=8lg+e), B=Q^T
    f32x4 st[4];
    #pragma unroll
    for (int f=0; f<4; ++f){
      int key = f*16 + lq;
      int sc = (h*4+lg) ^ (key&7);
      bf16x8 kf = *(const bf16x8*)&Klds[(key*16+sc)*8];
      st[f] = __builtin_amdgcn_mfma_f32_16x16x32_bf16(kf, qf, zero, 0,0,0);
    }
    // per-lane: 16 logits (keys 16f+4lg+r) for query lq
    float s[16]; float mt = -1e30f;
    #pragma unroll
    for (int f=0; f<4; ++f)
      #pragma unroll
      for (int r=0;r<4;r++){ float v = fmaf(st[f][r], scale, rel); s[f*4+r]=v; mt = fmaxf(mt,v); }
    mt = fmaxf(mt, __shfl_xor(mt,16));
    mt = fmaxf(mt, __shfl_xor(mt,32));
    float mnew  = fmaxf(mrow, mt);
    float alpha = __expf(mrow - mnew);        // first tile: exp(-1e30)=0
    float ps = 0.f;
    #pragma unroll
    for (int i=0;i<16;i++){ float p = __expf(s[i]-mnew); s[i]=p; ps += p; }
    ps += __shfl_xor(ps,16); ps += __shfl_xor(ps,32);
    lrow = lrow*alpha + ps;
    mrow = mnew;
    acc0 *= alpha; acc1 *= alpha;
    // P -> LDS [q][key], swizzled; 4 consecutive keys per ds_write_b64
    #pragma unroll
    for (int f=0; f<4; ++f){
      u32 lo = (u32)f2bf(s[f*4+0]) | ((u32)f2bf(s[f*4+1])<<16);
      u32 hi = (u32)f2bf(s[f*4+2]) | ((u32)f2bf(s[f*4+3])<<16);
      int cc = 2*f + (lg>>1);
      int sc = cc ^ (lq&7);
      uint2* p = (uint2*)((char*)Plds + wave*2048 + lq*128 + sc*16 + (lg&1)*8);
      *p = make_uint2(lo, hi);
    }
    // out^T += V^T . P^T   (A row=d=lq-based, B col=q=lq)
    #pragma unroll
    for (int c=0;c<2;c++){
      int scp = (4*c+lg) ^ (lq&7);
      bf16x8 pf = *(const bf16x8*)((const char*)Plds + wave*2048 + lq*128 + scp*16);
      int d0 = h*32 + lq;
      int sv0 = (4*c+lg) ^ (d0&7);
      bf16x8 vf0 = *(const bf16x8*)&VTlds[(d0*8+sv0)*8];
      acc0 = __builtin_amdgcn_mfma_f32_16x16x32_bf16(vf0, pf, acc0, 0,0,0);
      int d1 = h*32 + 16 + lq;
      int sv1 = (4*c+lg) ^ (d1&7);
      bf16x8 vf1 = *(const bf16x8*)&VTlds[(d1*8+sv1)*8];
      acc1 = __builtin_amdgcn_mfma_f32_16x16x32_bf16(vf1, pf, acc1, 0,0,0);
    }
  }
  float inv = 1.0f / lrow;
  float* outp = attnraw + (qrow0+lq)*128 + h*32 + 4*lg;  // acc row d = s2*16+4lg+r
  *(float4*)(outp)      = make_float4(acc0[0]*inv, acc0[1]*inv, acc0[2]*inv, acc0[3]*inv);
  *(float4*)(outp + 16) = make_float4(acc1[0]*inv, acc1[1]*inv, acc1[2]*inv, acc1[3]*inv);
}

// ---------------- attnraw@Wo + bo + deg + x -> res ; LN(g_ffn) then LN(g_f) -> hn ----------------
__global__ __launch_bounds__(256) void wo_res_ln_kernel(
    const float* __restrict__ attnraw,
    const float* __restrict__ Wo, const float* __restrict__ bo,
    const float* __restrict__ deg,
    const float* __restrict__ xa, const float* __restrict__ xb,
    const float* __restrict__ g1, const float* __restrict__ b1,
    const float* __restrict__ g2, const float* __restrict__ b2,
    float* __restrict__ res, float* __restrict__ hn)
{
  __shared__ float xs[16][129];
  const int t = threadIdx.x;
  const int row0 = blockIdx.x*16;
  const float* xin = attnraw + row0*128;
  #pragma unroll
  for (int i=0;i<2;i++){
    int id = t + i*256; int r = id>>5, c4 = (id&31)*4;
    float4 v = *(const float4*)(xin + r*128 + c4);
    xs[r][c4]=v.x; xs[r][c4+1]=v.y; xs[r][c4+2]=v.z; xs[r][c4+3]=v.w;
  }
  __syncthreads();
  const int col = t&127, rg = t>>7;
  float acc[8];
  #pragma unroll
  for (int r=0;r<8;r++) acc[r]=0.f;
  #pragma unroll 8
  for (int k=0;k<128;k++){
    float w = Wo[k*128+col];
    #pragma unroll
    for (int r=0;r<8;r++) acc[r] = fmaf(xs[r*2+rg][k], w, acc[r]);
  }
  const float* xres = (row0<4096)? (xa + row0*128) : (xb + (row0-4096)*128);
  float bov = bo[col];
  float rv[8];
  #pragma unroll
  for (int r=0;r<8;r++){
    int row = row0 + r*2 + rg;
    rv[r] = acc[r] + bov + deg[row] + xres[(r*2+rg)*128 + col];
  }
  __syncthreads();   // all xs reads done before overwrite
  #pragma unroll
  for (int r=0;r<8;r++){
    xs[r*2+rg][col] = rv[r];
    res[(row0 + r*2+rg)*128 + col] = rv[r];
  }
  __syncthreads();
  { // LN(g_ffn,b_ffn) then LN(g_f,b_f): second LN entirely in registers
    int r = t>>4, c0 = t&15;
    float s=0.f, s2=0.f;
    #pragma unroll
    for (int j=0;j<8;j++){ float v = xs[r][c0+j*16]; s+=v; s2+=v*v; }
    #pragma unroll
    for (int m=1;m<16;m<<=1){ s += __shfl_xor(s,m); s2 += __shfl_xor(s2,m); }
    float mean = s*0.0078125f;
    float var  = s2*0.0078125f - mean*mean;
    float rstd = rsqrtf(var + 1e-5f);
    float h8[8];
    #pragma unroll
    for (int j=0;j<8;j++){ int c=c0+j*16; h8[j] = (xs[r][c]-mean)*rstd*g1[c] + b1[c]; }
    s=0.f; s2=0.f;
    #pragma unroll
    for (int j=0;j<8;j++){ s+=h8[j]; s2+=h8[j]*h8[j]; }
    #pragma unroll
    for (int m=1;m<16;m<<=1){ s += __shfl_xor(s,m); s2 += __shfl_xor(s2,m); }
    float mean2 = s*0.0078125f;
    float var2  = s2*0.0078125f - mean2*mean2;
    float rstd2 = rsqrtf(var2 + 1e-5f);
    #pragma unroll
    for (int j=0;j<8;j++){ int c=c0+j*16; hn[(row0+r)*128 + c] = (h8[j]-mean2)*rstd2*g2[c] + b2[c]; }
  }
}

// ---------------- hn@W1+b1 -> GELU(exact) -> gact ----------------
__global__ __launch_bounds__(256) void ffn1_kernel(
    const float* __restrict__ hn, const float* __restrict__ W1,
    const float* __restrict__ b1, float* __restrict__ gact)
{
  __shared__ float xs[16][129];
  const int t = threadIdx.x;
  const int row0 = blockIdx.x*16;
  const float* xin = hn + row0*128;
  #pragma unroll
  for (int i=0;i<2;i++){
    int id = t + i*256; int r = id>>5, c4 = (id&31)*4;
    float4 v = *(const float4*)(xin + r*128 + c4);
    xs[r][c4]=v.x; xs[r][c4+1]=v.y; xs[r][c4+2]=v.z; xs[r][c4+3]=v.w;
  }
  __syncthreads();
  const int col = t&127, rg = t>>7;
  float acc[8];
  #pragma unroll
  for (int r=0;r<8;r++) acc[r]=0.f;
  #pragma unroll 8
  for (int k=0;k<128;k++){
    float w = W1[k*128+col];
    #pragma unroll
    for (int r=0;r<8;r++) acc[r] = fmaf(xs[r*2+rg][k], w, acc[r]);
  }
  float bv = b1[col];
  #pragma unroll
  for (int r=0;r<8;r++){
    float v = acc[r] + bv;
    gact[(row0 + r*2+rg)*128 + col] = 0.5f*v*(1.f + erff(v*0.70710678118654752f));
  }
}

// ---------------- gact@W2+b2+res -> d_out ([2,4096,128] flat = rows 0..8191) ----------------
__global__ __launch_bounds__(256) void ffn2_kernel(
    const float* __restrict__ gact, const float* __restrict__ W2,
    const float* __restrict__ b2, const float* __restrict__ res,
    float* __restrict__ out)
{
  __shared__ float xs[16][129];
  const int t = threadIdx.x;
  const int row0 = blockIdx.x*16;
  const float* xin = gact + row0*128;
  #pragma unroll
  for (int i=0;i<2;i++){
    int id = t + i*256; int r = id>>5, c4 = (id&31)*4;
    float4 v = *(const float4*)(xin + r*128 + c4);
    xs[r][c4]=v.x; xs[r][c4+1]=v.y; xs[r][c4+2]=v.z; xs[r][c4+3]=v.w;
  }
  __syncthreads();
  const int col = t&127, rg = t>>7;
  float acc[8];
  #pragma unroll
  for (int r=0;r<8;r++) acc[r]=0.f;
  #pragma unroll 8
  for (int k=0;k<128;k++){
    float w = W2[k*128+col];
    #pragma unroll
    for (int r=0;r<8;r++) acc[r] = fmaf(xs[r*2+rg][k], w, acc[r]);
  }
  float bv = b2[col];
  #pragma unroll
  for (int r=0;r<8;r++){
    int row = row0 + r*2 + rg;
    out[row*128 + col] = acc[r] + bv + res[row*128 + col];
  }
}

extern "C" void kernel_launch(void* const* d_in, const int* in_sizes, int n_in,
                              void* d_out, int out_size, void* d_ws, size_t ws_size,
                              hipStream_t stream) {
  const float* xa  = (const float*)d_in[0];
  const float* xb  = (const float*)d_in[1];
  const int*   eab = (const int*)d_in[2];
  const int*   eba = (const int*)d_in[3];
  const float* Wq  = (const float*)d_in[4];   const float* bq = (const float*)d_in[5];
  const float* Wk  = (const float*)d_in[6];   const float* bk = (const float*)d_in[7];
  const float* Wv  = (const float*)d_in[8];   const float* bv = (const float*)d_in[9];
  const float* Wo  = (const float*)d_in[10];  const float* bo = (const float*)d_in[11];
  const float* ga  = (const float*)d_in[12];  const float* ba = (const float*)d_in[13];
  const float* gfn = (const float*)d_in[14];  const float* bfn= (const float*)d_in[15];
  const float* gf  = (const float*)d_in[16];  const float* bf = (const float*)d_in[17];
  const float* W1  = (const float*)d_in[18];  const float* b1 = (const float*)d_in[19];
  const float* W2  = (const float*)d_in[20];  const float* b2 = (const float*)d_in[21];
  const float* rab = (const float*)d_in[22];
  const float* rba = (const float*)d_in[23];
  float* out = (float*)d_out;

  // workspace layout (24.03 MB total)
  char* w = (char*)d_ws;
  float* deg     = (float*)w;                          // 32 KB
  u16*   Qb      = (u16*)(w + 32768);                  // 2 MB each
  u16*   Kb      = Qb + NEL;
  u16*   Vb      = Kb + NEL;
  u16*   VT      = Vb + NEL;
  float* attnraw = (float*)(w + 32768 + 4u*2u*NEL);    // 4 MB each
  float* res     = attnraw + NEL;
  float* hn      = res + NEL;
  float* gact    = hn + NEL;

  hipMemsetAsync(deg, 0, 8192*sizeof(float), stream);
  deg_kernel<<<256, 256, 0, stream>>>(eab, eba, deg);
  ln_qkv_kernel<<<512, 256, 0, stream>>>(xa, xb, ga, ba, Wq, bq, Wk, bk, Wv, bv, Qb, Kb, Vb);
  transpose_kernel<<<dim3(128,2), 256, 0, stream>>>(Vb, VT);
  attn_kernel<<<dim3(256,2), 256, 0, stream>>>(Qb, Kb, VT, rab, rba, attnraw);
  wo_res_ln_kernel<<<512, 256, 0, stream>>>(attnraw, Wo, bo, deg, xa, xb, gfn, bfn, gf, bf, res, hn);
  ffn1_kernel<<<512, 256, 0, stream>>>(hn, W1, b1, gact);
  ffn2_kernel<<<512, 256, 0, stream>>>(gact, W2, b2, res, out);
}

// Round 2
// 278.540 us; speedup vs baseline: 1.0841x; 1.0841x over previous
//
#include <hip/hip_runtime.h>

typedef unsigned short u16;
typedef unsigned int   u32;
typedef __attribute__((ext_vector_type(8))) short bf16x8;  // 8 bf16 (4 VGPRs)
typedef __attribute__((ext_vector_type(4))) float f32x4;   // MFMA acc

#define NEL (8192*128)

// async global->LDS, 16B per lane, LDS dest = wave-uniform base + lane*16
#define ASYNC16(ldsptr, gptr) __builtin_amdgcn_global_load_lds( \
    (const __attribute__((address_space(1))) u32*)(gptr), \
    (__attribute__((address_space(3))) u32*)(ldsptr), 16, 0, 0)

__device__ __forceinline__ u16 f2bf(float f){
  u32 u = __builtin_bit_cast(u32, f);
  u = (u + 0x7FFFu + ((u >> 16) & 1u)) >> 16;  // RNE
  return (u16)u;
}
__device__ __forceinline__ u32 pk2(float a, float b){  // lo=bf16(a), hi=bf16(b)
  u32 r;
  asm("v_cvt_pk_bf16_f32 %0, %1, %2" : "=v"(r) : "v"(a), "v"(b));
  return r;
}

// ---------------- degrees: 4 atomic streams, f32 adds of 1.0 (exact) ----------------
__global__ __launch_bounds__(256) void deg_kernel(const int* __restrict__ eab,
                                                  const int* __restrict__ eba,
                                                  float* __restrict__ deg){
  int e = blockIdx.x*256 + threadIdx.x;
  if (e < 65536){
    atomicAdd(&deg[eab[e]],              1.f);
    atomicAdd(&deg[4096 + eab[65536+e]], 1.f);
    atomicAdd(&deg[4096 + eba[e]],       1.f);
    atomicAdd(&deg[eba[65536+e]],        1.f);
  }
}

// ---------------- LN(x); x@{Wq,Wk,Wv}+b -> bf16 Q(pre-scaled),K row-major; V -> V^T ----------------
__global__ __launch_bounds__(256) void ln_qkv_kernel(
    const float* __restrict__ xa, const float* __restrict__ xb,
    const float* __restrict__ g, const float* __restrict__ b,
    const float* __restrict__ Wq, const float* __restrict__ bq,
    const float* __restrict__ Wk, const float* __restrict__ bk,
    const float* __restrict__ Wv, const float* __restrict__ bv,
    u16* __restrict__ Qb, u16* __restrict__ Kb, u16* __restrict__ VT)
{
  __shared__ float xs[16][129];
  __shared__ __align__(16) u16 vtb[128][16];
  const int t = threadIdx.x;
  const int row0 = blockIdx.x*16;
  const float* x = (row0 < 4096) ? (xa + row0*128) : (xb + (row0-4096)*128);
  #pragma unroll
  for (int i=0;i<2;i++){
    int id = t + i*256; int r = id>>5, c4 = (id&31)*4;
    float4 v = *(const float4*)(x + r*128 + c4);
    xs[r][c4]=v.x; xs[r][c4+1]=v.y; xs[r][c4+2]=v.z; xs[r][c4+3]=v.w;
  }
  __syncthreads();
  { // LN: 16 threads/row
    int r = t>>4, c0 = t&15;
    float s=0.f, s2=0.f;
    #pragma unroll
    for (int j=0;j<8;j++){ float v = xs[r][c0+j*16]; s+=v; s2+=v*v; }
    #pragma unroll
    for (int m=1;m<16;m<<=1){ s += __shfl_xor(s,m); s2 += __shfl_xor(s2,m); }
    float mean = s*0.0078125f;
    float var  = s2*0.0078125f - mean*mean;
    float rstd = rsqrtf(var + 1e-5f);
    #pragma unroll
    for (int j=0;j<8;j++){ int c=c0+j*16; xs[r][c] = (xs[r][c]-mean)*rstd*g[c] + b[c]; }
  }
  __syncthreads();
  const int col = t&127, rg = t>>7;
  float aq[8], ak[8], av[8];
  #pragma unroll
  for (int r=0;r<8;r++){ aq[r]=0.f; ak[r]=0.f; av[r]=0.f; }
  #pragma unroll 8
  for (int k=0;k<128;k++){
    float wq = Wq[k*128+col], wk = Wk[k*128+col], wv = Wv[k*128+col];
    #pragma unroll
    for (int r=0;r<8;r++){
      float xv = xs[r*2+rg][k];
      aq[r] = fmaf(xv,wq,aq[r]); ak[r] = fmaf(xv,wk,ak[r]); av[r] = fmaf(xv,wv,av[r]);
    }
  }
  const float QSC = 0.17677669529663687f * 1.4426950408889634f; // 1/sqrt(32) * log2(e)
  float bqv=bq[col], bkv=bk[col], bvv=bv[col];
  #pragma unroll
  for (int r=0;r<8;r++){
    int row = row0 + r*2 + rg;
    Qb[row*128+col] = f2bf((aq[r]+bqv)*QSC);
    Kb[row*128+col] = f2bf(ak[r]+bkv);
    vtb[col][r*2+rg] = f2bf(av[r]+bvv);
  }
  __syncthreads();
  { // V^T global write: thread -> (col c = t>>1, half = t&1)
    int c = t>>1, half = t&1;
    bf16x8 v = *(const bf16x8*)&vtb[c][half*8];
    *(bf16x8*)(VT + c*8192 + row0 + half*8) = v;
  }
}

// ---------------- flash attention: per-head blocks, m==0 softmax, MFMA row-sum ----------------
// block = 4 waves, 1 head, 64 queries (wave w -> 16 q). KBLK=128 keys/tile, 32 tiles.
// S^T = K.Q^T (Q pre-scaled by 1/sqrt(D)*log2e) -> exp2 directly, no max tracking.
// out^T = V^T.P^T; l-row via ones-A MFMA. global_load_lds staging, 2-phase pipeline.
__global__ __launch_bounds__(256) void attn_kernel(
    const u16* __restrict__ Qb, const u16* __restrict__ Kb,
    const u16* __restrict__ VT, float* __restrict__ attnraw)
{
  __shared__ __align__(16) u16 Klds[2][4096];   // 128 keys x 4 chunks(16B), linear
  __shared__ __align__(16) u16 Vlds[2][4096];   // 32 d x 16 chunks, chunk j stored at sj=j^ (d&15)
  __shared__ __align__(16) u16 Plds[4][2048];   // per wave: 16 q x 16 chunks, sj = j ^ q
  const int t = threadIdx.x, wave = t>>6, lane = t&63;
  const int lq = lane&15, lg = lane>>4;
  const int h = blockIdx.y, dir = blockIdx.z;
  const int q = blockIdx.x*64 + wave*16 + lq + (dir ? 4096 : 0);
  const int kvb0 = dir ? 0 : 4096;

  bf16x8 qf = *(const bf16x8*)(Qb + q*128 + h*32 + lg*8);
  f32x4 acc0 = {0,0,0,0}, acc1 = {0,0,0,0}, accL = {0,0,0,0};
  bf16x8 ones;
  #pragma unroll
  for (int i=0;i<8;i++) ones[i] = (short)0x3F80;   // bf16 1.0

  // per-thread staging sources (advance per tile)
  const u16* gk = Kb + (kvb0 + (t>>2))*128 + h*32 + (t&3)*8;
  const u16* gv = VT + (h*32 + (t>>4))*8192 + kvb0 + ((t&15)^(t>>4))*8;

  // prologue: stage tile 0 into buf 0
  ASYNC16(&Klds[0][t*8],      gk);
  ASYNC16(&Klds[0][t*8+2048], gk + 8192);       // +64 keys
  ASYNC16(&Vlds[0][t*8],      gv);
  ASYNC16(&Vlds[0][t*8+2048], gv + 131072);     // +16 d rows
  asm volatile("s_waitcnt vmcnt(0)" ::: "memory");
  __builtin_amdgcn_s_barrier();

  int cur = 0;
  for (int kt=0; kt<32; ++kt){
    if (kt < 31){
      gk += 16384; gv += 128;                   // next tile
      int nb = cur^1;
      ASYNC16(&Klds[nb][t*8],      gk);
      ASYNC16(&Klds[nb][t*8+2048], gk + 8192);
      ASYNC16(&Vlds[nb][t*8],      gv);
      ASYNC16(&Vlds[nb][t*8+2048], gv + 131072);
    }
    const u16* KL = Klds[cur];
    const u16* VL = Vlds[cur];
    u16* PL = Plds[wave] + lq*128;              // this lane's q-row (256B)
    // S^T (8 MFMA) -> exp2 -> pack -> P LDS
    #pragma unroll
    for (int f=0; f<8; ++f){
      bf16x8 kf = *(const bf16x8*)(KL + (f*16+lq)*32 + lg*8);
      f32x4 st = __builtin_amdgcn_mfma_f32_16x16x32_bf16(kf, qf, (f32x4){0.f,0.f,0.f,0.f}, 0,0,0);
      float p0 = __builtin_amdgcn_exp2f(st[0]);
      float p1 = __builtin_amdgcn_exp2f(st[1]);
      float p2 = __builtin_amdgcn_exp2f(st[2]);
      float p3 = __builtin_amdgcn_exp2f(st[3]);
      int j = f*2 + (lg>>1);                    // keys f*16+4lg.. -> chunk
      *(uint2*)(PL + ((j ^ lq)<<3) + (lg&1)*4) = make_uint2(pk2(p0,p1), pk2(p2,p3));
    }
    // PV + l-sum: 12 MFMA
    #pragma unroll
    for (int kc=0; kc<4; ++kc){
      int sj = (kc*4+lg) ^ lq;
      bf16x8 pf  = *(const bf16x8*)(PL + (sj<<3));
      bf16x8 vf0 = *(const bf16x8*)(VL + lq*128      + (sj<<3));
      bf16x8 vf1 = *(const bf16x8*)(VL + (16+lq)*128 + (sj<<3));
      acc0 = __builtin_amdgcn_mfma_f32_16x16x32_bf16(vf0,  pf, acc0, 0,0,0);
      acc1 = __builtin_amdgcn_mfma_f32_16x16x32_bf16(vf1,  pf, acc1, 0,0,0);
      accL = __builtin_amdgcn_mfma_f32_16x16x32_bf16(ones, pf, accL, 0,0,0);
    }
    asm volatile("s_waitcnt vmcnt(0)" ::: "memory");
    __builtin_amdgcn_s_barrier();
    cur ^= 1;
  }
  float inv = __builtin_amdgcn_rcpf(accL[0]);
  float* outp = attnraw + q*128 + h*32 + 4*lg;  // d = s2*16 + 4lg + r
  *(float4*)(outp)      = make_float4(acc0[0]*inv, acc0[1]*inv, acc0[2]*inv, acc0[3]*inv);
  *(float4*)(outp + 16) = make_float4(acc1[0]*inv, acc1[1]*inv, acc1[2]*inv, acc1[3]*inv);
}

// ---------------- fused tail: @Wo+bo+deg+x -> res ; LN;LN ; @W1+b1 -> gelu ; @W2+b2+res -> out ----------------
__global__ __launch_bounds__(256) void tail_kernel(
    const float* __restrict__ attnraw,
    const float* __restrict__ Wo, const float* __restrict__ bo,
    const float* __restrict__ deg,
    const float* __restrict__ xa, const float* __restrict__ xb,
    const float* __restrict__ gf1, const float* __restrict__ bf1,
    const float* __restrict__ gf2, const float* __restrict__ bf2,
    const float* __restrict__ W1, const float* __restrict__ b1,
    const float* __restrict__ W2, const float* __restrict__ b2,
    float* __restrict__ out)
{
  __shared__ float xs[16][129];
  const int t = threadIdx.x;
  const int row0 = blockIdx.x*16;
  const int col = t&127, rg = t>>7;
  // phase 0: load attnraw
  #pragma unroll
  for (int i=0;i<2;i++){
    int id = t + i*256; int r = id>>5, c4 = (id&31)*4;
    float4 v = *(const float4*)(attnraw + (row0+r)*128 + c4);
    xs[r][c4]=v.x; xs[r][c4+1]=v.y; xs[r][c4+2]=v.z; xs[r][c4+3]=v.w;
  }
  __syncthreads();
  // phase 1: @Wo
  float acc[8];
  #pragma unroll
  for (int r=0;r<8;r++) acc[r]=0.f;
  #pragma unroll 8
  for (int k=0;k<128;k++){
    float w = Wo[k*128+col];
    #pragma unroll
    for (int r=0;r<8;r++) acc[r] = fmaf(xs[r*2+rg][k], w, acc[r]);
  }
  const float* xres = (row0<4096)? (xa + row0*128) : (xb + (row0-4096)*128);
  float bov = bo[col];
  float rv[8];
  #pragma unroll
  for (int r=0;r<8;r++)
    rv[r] = acc[r] + bov + deg[row0 + r*2 + rg] + xres[(r*2+rg)*128 + col];
  __syncthreads();
  #pragma unroll
  for (int r=0;r<8;r++) xs[r*2+rg][col] = rv[r];
  __syncthreads();
  // phase 2: LN(g_ffn) then LN(g_f), in place
  {
    int r = t>>4, c0 = t&15;
    float s=0.f, s2=0.f;
    #pragma unroll
    for (int j=0;j<8;j++){ float v = xs[r][c0+j*16]; s+=v; s2+=v*v; }
    #pragma unroll
    for (int m=1;m<16;m<<=1){ s += __shfl_xor(s,m); s2 += __shfl_xor(s2,m); }
    float mean = s*0.0078125f;
    float var  = s2*0.0078125f - mean*mean;
    float rstd = rsqrtf(var + 1e-5f);
    float h8[8];
    #pragma unroll
    for (int j=0;j<8;j++){ int c=c0+j*16; h8[j] = (xs[r][c]-mean)*rstd*gf1[c] + bf1[c]; }
    s=0.f; s2=0.f;
    #pragma unroll
    for (int j=0;j<8;j++){ s+=h8[j]; s2+=h8[j]*h8[j]; }
    #pragma unroll
    for (int m=1;m<16;m<<=1){ s += __shfl_xor(s,m); s2 += __shfl_xor(s2,m); }
    float mean2 = s*0.0078125f;
    float var2  = s2*0.0078125f - mean2*mean2;
    float rstd2 = rsqrtf(var2 + 1e-5f);
    #pragma unroll
    for (int j=0;j<8;j++){ int c=c0+j*16; xs[r][c] = (h8[j]-mean2)*rstd2*gf2[c] + bf2[c]; }
  }
  __syncthreads();
  // phase 3: @W1 + gelu(exact)
  #pragma unroll
  for (int r=0;r<8;r++) acc[r]=0.f;
  #pragma unroll 8
  for (int k=0;k<128;k++){
    float w = W1[k*128+col];
    #pragma unroll
    for (int r=0;r<8;r++) acc[r] = fmaf(xs[r*2+rg][k], w, acc[r]);
  }
  float b1v = b1[col];
  float gv[8];
  #pragma unroll
  for (int r=0;r<8;r++){
    float v = acc[r] + b1v;
    gv[r] = 0.5f*v*(1.f + erff(v*0.70710678118654752f));
  }
  __syncthreads();
  #pragma unroll
  for (int r=0;r<8;r++) xs[r*2+rg][col] = gv[r];
  __syncthreads();
  // phase 4: @W2 + b2 + res
  #pragma unroll
  for (int r=0;r<8;r++) acc[r]=0.f;
  #pragma unroll 8
  for (int k=0;k<128;k++){
    float w = W2[k*128+col];
    #pragma unroll
    for (int r=0;r<8;r++) acc[r] = fmaf(xs[r*2+rg][k], w, acc[r]);
  }
  float b2v = b2[col];
  #pragma unroll
  for (int r=0;r<8;r++){
    int row = row0 + r*2 + rg;
    out[row*128 + col] = acc[r] + b2v + rv[r];
  }
}

extern "C" void kernel_launch(void* const* d_in, const int* in_sizes, int n_in,
                              void* d_out, int out_size, void* d_ws, size_t ws_size,
                              hipStream_t stream) {
  const float* xa  = (const float*)d_in[0];
  const float* xb  = (const float*)d_in[1];
  const int*   eab = (const int*)d_in[2];
  const int*   eba = (const int*)d_in[3];
  const float* Wq  = (const float*)d_in[4];   const float* bq = (const float*)d_in[5];
  const float* Wk  = (const float*)d_in[6];   const float* bk = (const float*)d_in[7];
  const float* Wv  = (const float*)d_in[8];   const float* bv = (const float*)d_in[9];
  const float* Wo  = (const float*)d_in[10];  const float* bo = (const float*)d_in[11];
  const float* ga  = (const float*)d_in[12];  const float* ba = (const float*)d_in[13];
  const float* gfn = (const float*)d_in[14];  const float* bfn= (const float*)d_in[15];
  const float* gf  = (const float*)d_in[16];  const float* bf = (const float*)d_in[17];
  const float* W1  = (const float*)d_in[18];  const float* b1 = (const float*)d_in[19];
  const float* W2  = (const float*)d_in[20];  const float* b2 = (const float*)d_in[21];
  float* out = (float*)d_out;

  // workspace: deg 32KB | Qb,Kb,VT 2MB each | attnraw 4MB  (~10.3MB)
  char* w = (char*)d_ws;
  float* deg     = (float*)w;
  u16*   Qb      = (u16*)(w + 32768);
  u16*   Kb      = Qb + NEL;
  u16*   VT      = Kb + NEL;
  float* attnraw = (float*)(VT + NEL);

  hipMemsetAsync(deg, 0, 8192*sizeof(float), stream);
  deg_kernel<<<256, 256, 0, stream>>>(eab, eba, deg);
  ln_qkv_kernel<<<512, 256, 0, stream>>>(xa, xb, ga, ba, Wq, bq, Wk, bk, Wv, bv, Qb, Kb, VT);
  attn_kernel<<<dim3(64,4,2), 256, 0, stream>>>(Qb, Kb, VT, attnraw);
  tail_kernel<<<512, 256, 0, stream>>>(attnraw, Wo, bo, deg, xa, xb,
                                       gfn, bfn, gf, bf, W1, b1, W2, b2, out);
}

// Round 3
// 195.294 us; speedup vs baseline: 1.5462x; 1.4263x over previous
//
#include <hip/hip_runtime.h>

typedef unsigned short u16;
typedef unsigned int   u32;
typedef __attribute__((ext_vector_type(8))) short bf16x8;  // 8 bf16 (4 VGPRs)
typedef __attribute__((ext_vector_type(4))) float f32x4;   // MFMA acc

#define NEL (8192*128)

// async global->LDS, 16B per lane, LDS dest = wave-uniform base + lane*16
#define ASYNC16(ldsptr, gptr) __builtin_amdgcn_global_load_lds( \
    (const __attribute__((address_space(1))) u32*)(gptr), \
    (__attribute__((address_space(3))) u32*)(ldsptr), 16, 0, 0)

__device__ __forceinline__ u16 f2bf(float f){
  u32 u = __builtin_bit_cast(u32, f);
  u = (u + 0x7FFFu + ((u >> 16) & 1u)) >> 16;  // RNE
  return (u16)u;
}
__device__ __forceinline__ u32 pk2(float a, float b){  // lo=bf16(a), hi=bf16(b)
  u32 r;
  asm("v_cvt_pk_bf16_f32 %0, %1, %2" : "=v"(r) : "v"(a), "v"(b));
  return r;
}

// ---------------- prep: degree atomics (blocks 0..255) + weight bf16 transpose (256..351) ----------------
// WT layout: [6][128][128] bf16, WT[w][n][k] = W_w[k][n]  (k-contiguous for B-frags)
__global__ __launch_bounds__(256) void prep_kernel(
    const int* __restrict__ eab, const int* __restrict__ eba, float* __restrict__ deg,
    const float* __restrict__ Wq, const float* __restrict__ Wk, const float* __restrict__ Wv,
    const float* __restrict__ Wo, const float* __restrict__ W1, const float* __restrict__ W2,
    u16* __restrict__ WT)
{
  __shared__ float tile[32][33];
  const int b = blockIdx.x, t = threadIdx.x;
  if (b < 256){
    int e = b*256 + t;
    atomicAdd(&deg[eab[e]],              1.f);
    atomicAdd(&deg[4096 + eab[65536+e]], 1.f);
    atomicAdd(&deg[4096 + eba[e]],       1.f);
    atomicAdd(&deg[eba[65536+e]],        1.f);
  } else {
    int id = b - 256;                 // 0..95 = 6 W x 16 tiles(32x32)
    int w = id >> 4, tt = id & 15, tr = tt >> 2, tc = tt & 3;
    const float* W = (w==0)?Wq:(w==1)?Wk:(w==2)?Wv:(w==3)?Wo:(w==4)?W1:W2;
    int r = t >> 3, c4 = (t&7)*4;
    float4 v = *(const float4*)(W + (tr*32 + r)*128 + tc*32 + c4);
    tile[r][c4]=v.x; tile[r][c4+1]=v.y; tile[r][c4+2]=v.z; tile[r][c4+3]=v.w;
    __syncthreads();
    int n = t >> 3, k4 = (t&7)*4;     // write WT[w][tc*32+n][tr*32+k4..+3]
    u32 lo = pk2(tile[k4+0][n], tile[k4+1][n]);
    u32 hi = pk2(tile[k4+2][n], tile[k4+3][n]);
    *(uint2*)(WT + w*16384 + (tc*32+n)*128 + tr*32 + k4) = make_uint2(lo, hi);
  }
}

// ---------------- LN(x); MFMA x@{Wq,Wk,Wv}+b -> bf16 Q(pre-scaled),K,V^T ----------------
// 512 blocks x 256 thr (4 waves), 16 rows/block; wave w -> cols 32w..32w+31
__global__ __launch_bounds__(256) void ln_qkv_kernel(
    const float* __restrict__ xa, const float* __restrict__ xb,
    const float* __restrict__ g, const float* __restrict__ bvec,
    const u16* __restrict__ WT,
    const float* __restrict__ bq, const float* __restrict__ bk, const float* __restrict__ bv,
    u16* __restrict__ Qb, u16* __restrict__ Kb, u16* __restrict__ VT)
{
  __shared__ float xs[16][132];
  __shared__ __align__(16) u16 abf[16][128];   // bf16 A-tile, 16B chunks XOR-swizzled
  __shared__ __align__(16) u16 vtb[128][24];   // V^T bounce (stride 48B)
  const int t = threadIdx.x, lane = t&63, wave = t>>6;
  const int lq = lane&15, lg = lane>>4;
  const int row0 = blockIdx.x*16;
  const float* x = (row0 < 4096) ? (xa + row0*128) : (xb + (row0-4096)*128);
  #pragma unroll
  for (int i=0;i<2;i++){
    int id = t + i*256; int r = id>>5, c4 = (id&31)*4;
    float4 v = *(const float4*)(x + r*128 + c4);
    xs[r][c4]=v.x; xs[r][c4+1]=v.y; xs[r][c4+2]=v.z; xs[r][c4+3]=v.w;
  }
  __syncthreads();
  { // LN, 16 threads/row; write bf16 swizzled A-tile
    int r = t>>4, c0 = t&15;
    float s=0.f, s2=0.f;
    #pragma unroll
    for (int j=0;j<8;j++){ float v = xs[r][c0+j*16]; s+=v; s2+=v*v; }
    #pragma unroll
    for (int m=1;m<16;m<<=1){ s += __shfl_xor(s,m); s2 += __shfl_xor(s2,m); }
    float mean = s*0.0078125f;
    float var  = s2*0.0078125f - mean*mean;
    float rstd = rsqrtf(var + 1e-5f);
    #pragma unroll
    for (int j=0;j<8;j++){
      int c = c0 + j*16;
      float h = (xs[r][c]-mean)*rstd*g[c] + bvec[c];
      int sj = (c>>3) ^ (r&7);
      abf[r][sj*8 + (c&7)] = f2bf(h);
    }
  }
  __syncthreads();
  // A-frags: row=lq, k=s*32+lg*8
  bf16x8 af[4];
  #pragma unroll
  for (int s=0;s<4;s++){
    int sj = (s*4+lg) ^ (lq&7);
    af[s] = *(const bf16x8*)&abf[lq][sj*8];
  }
  const int cb = wave*32;
  const float QSC = 0.17677669529663687f * 1.4426950408889634f; // 1/sqrt(32)*log2e
  #pragma unroll
  for (int m=0;m<3;m++){
    const u16* Wg = WT + m*16384;
    bf16x8 bf[2][4];
    #pragma unroll
    for (int ct=0;ct<2;ct++)
      #pragma unroll
      for (int s=0;s<4;s++)
        bf[ct][s] = *(const bf16x8*)(Wg + (cb+ct*16+lq)*128 + s*32 + lg*8);
    f32x4 acc[2] = {{0,0,0,0},{0,0,0,0}};
    #pragma unroll
    for (int ct=0;ct<2;ct++)
      #pragma unroll
      for (int s=0;s<4;s++)
        acc[ct] = __builtin_amdgcn_mfma_f32_16x16x32_bf16(af[s], bf[ct][s], acc[ct], 0,0,0);
    // epilogue: C col=cb+ct*16+lq, row=4*lg+r
    #pragma unroll
    for (int ct=0;ct<2;ct++){
      int col = cb + ct*16 + lq;
      if (m==0){
        float bb = bq[col];
        #pragma unroll
        for (int r=0;r<4;r++)
          Qb[(row0+4*lg+r)*128 + col] = f2bf((acc[ct][r]+bb)*QSC);
      } else if (m==1){
        float bb = bk[col];
        #pragma unroll
        for (int r=0;r<4;r++)
          Kb[(row0+4*lg+r)*128 + col] = f2bf(acc[ct][r]+bb);
      } else {
        float bb = bv[col];
        #pragma unroll
        for (int r=0;r<4;r++)
          vtb[col][4*lg+r] = f2bf(acc[ct][r]+bb);
      }
    }
  }
  __syncthreads();
  { // V^T global write: c = t>>1, half = t&1 (16B each)
    int c = t>>1, half = t&1;
    bf16x8 v = *(const bf16x8*)&vtb[c][half*8];
    *(bf16x8*)(VT + c*8192 + row0 + half*8) = v;
  }
}

// ---------------- flash attention (unchanged from R2) ----------------
__global__ __launch_bounds__(256) void attn_kernel(
    const u16* __restrict__ Qb, const u16* __restrict__ Kb,
    const u16* __restrict__ VT, float* __restrict__ attnraw)
{
  __shared__ __align__(16) u16 Klds[2][4096];
  __shared__ __align__(16) u16 Vlds[2][4096];
  __shared__ __align__(16) u16 Plds[4][2048];
  const int t = threadIdx.x, wave = t>>6, lane = t&63;
  const int lq = lane&15, lg = lane>>4;
  const int h = blockIdx.y, dir = blockIdx.z;
  const int q = blockIdx.x*64 + wave*16 + lq + (dir ? 4096 : 0);
  const int kvb0 = dir ? 0 : 4096;

  bf16x8 qf = *(const bf16x8*)(Qb + q*128 + h*32 + lg*8);
  f32x4 acc0 = {0,0,0,0}, acc1 = {0,0,0,0}, accL = {0,0,0,0};
  bf16x8 ones;
  #pragma unroll
  for (int i=0;i<8;i++) ones[i] = (short)0x3F80;

  const u16* gk = Kb + (kvb0 + (t>>2))*128 + h*32 + (t&3)*8;
  const u16* gv = VT + (h*32 + (t>>4))*8192 + kvb0 + ((t&15)^(t>>4))*8;

  ASYNC16(&Klds[0][t*8],      gk);
  ASYNC16(&Klds[0][t*8+2048], gk + 8192);
  ASYNC16(&Vlds[0][t*8],      gv);
  ASYNC16(&Vlds[0][t*8+2048], gv + 131072);
  asm volatile("s_waitcnt vmcnt(0)" ::: "memory");
  __builtin_amdgcn_s_barrier();

  int cur = 0;
  for (int kt=0; kt<32; ++kt){
    if (kt < 31){
      gk += 16384; gv += 128;
      int nb = cur^1;
      ASYNC16(&Klds[nb][t*8],      gk);
      ASYNC16(&Klds[nb][t*8+2048], gk + 8192);
      ASYNC16(&Vlds[nb][t*8],      gv);
      ASYNC16(&Vlds[nb][t*8+2048], gv + 131072);
    }
    const u16* KL = Klds[cur];
    const u16* VL = Vlds[cur];
    u16* PL = Plds[wave] + lq*128;
    #pragma unroll
    for (int f=0; f<8; ++f){
      bf16x8 kf = *(const bf16x8*)(KL + (f*16+lq)*32 + lg*8);
      f32x4 st = __builtin_amdgcn_mfma_f32_16x16x32_bf16(kf, qf, (f32x4){0.f,0.f,0.f,0.f}, 0,0,0);
      float p0 = __builtin_amdgcn_exp2f(st[0]);
      float p1 = __builtin_amdgcn_exp2f(st[1]);
      float p2 = __builtin_amdgcn_exp2f(st[2]);
      float p3 = __builtin_amdgcn_exp2f(st[3]);
      int j = f*2 + (lg>>1);
      *(uint2*)(PL + ((j ^ lq)<<3) + (lg&1)*4) = make_uint2(pk2(p0,p1), pk2(p2,p3));
    }
    #pragma unroll
    for (int kc=0; kc<4; ++kc){
      int sj = (kc*4+lg) ^ lq;
      bf16x8 pf  = *(const bf16x8*)(PL + (sj<<3));
      bf16x8 vf0 = *(const bf16x8*)(VL + lq*128      + (sj<<3));
      bf16x8 vf1 = *(const bf16x8*)(VL + (16+lq)*128 + (sj<<3));
      acc0 = __builtin_amdgcn_mfma_f32_16x16x32_bf16(vf0,  pf, acc0, 0,0,0);
      acc1 = __builtin_amdgcn_mfma_f32_16x16x32_bf16(vf1,  pf, acc1, 0,0,0);
      accL = __builtin_amdgcn_mfma_f32_16x16x32_bf16(ones, pf, accL, 0,0,0);
    }
    asm volatile("s_waitcnt vmcnt(0)" ::: "memory");
    __builtin_amdgcn_s_barrier();
    cur ^= 1;
  }
  float inv = __builtin_amdgcn_rcpf(accL[0]);
  float* outp = attnraw + q*128 + h*32 + 4*lg;
  *(float4*)(outp)      = make_float4(acc0[0]*inv, acc0[1]*inv, acc0[2]*inv, acc0[3]*inv);
  *(float4*)(outp + 16) = make_float4(acc1[0]*inv, acc1[1]*inv, acc1[2]*inv, acc1[3]*inv);
}

// ---------------- MFMA tail: @Wo+bo+deg+x -> res ; LN;LN ; @W1+gelu ; @W2+b2+res -> out ----------------
// 512 blocks x 256 thr (4 waves), 16 rows; wave w -> cols 32w..+31
__global__ __launch_bounds__(256) void tail_kernel(
    const float* __restrict__ attnraw, const u16* __restrict__ WT,
    const float* __restrict__ bo, const float* __restrict__ deg,
    const float* __restrict__ xa, const float* __restrict__ xb,
    const float* __restrict__ gf1, const float* __restrict__ bf1,
    const float* __restrict__ gf2, const float* __restrict__ bf2,
    const float* __restrict__ b1, const float* __restrict__ b2,
    float* __restrict__ out)
{
  __shared__ __align__(16) u16 abf[16][128];
  __shared__ float rs[16][132];
  const int t = threadIdx.x, lane = t&63, wave = t>>6;
  const int lq = lane&15, lg = lane>>4;
  const int row0 = blockIdx.x*16;
  const int cb = wave*32;

  { // stage attnraw -> bf16 swizzled A-tile (no f32 bounce)
    int r = t>>4, j = t&15;
    const float* p = attnraw + (row0+r)*128 + j*8;
    float4 v0 = *(const float4*)(p), v1 = *(const float4*)(p+4);
    bf16x8 bv;
    bv[0]=(short)f2bf(v0.x); bv[1]=(short)f2bf(v0.y); bv[2]=(short)f2bf(v0.z); bv[3]=(short)f2bf(v0.w);
    bv[4]=(short)f2bf(v1.x); bv[5]=(short)f2bf(v1.y); bv[6]=(short)f2bf(v1.z); bv[7]=(short)f2bf(v1.w);
    int sj = j ^ (r&7);
    *(bf16x8*)&abf[r][sj*8] = bv;
  }
  __syncthreads();

  bf16x8 af[4];
  #pragma unroll
  for (int s=0;s<4;s++){ int sj = (s*4+lg) ^ (lq&7); af[s] = *(const bf16x8*)&abf[lq][sj*8]; }

  // GEMM1: @Wo
  f32x4 acc[2] = {{0,0,0,0},{0,0,0,0}};
  {
    const u16* Wg = WT + 3*16384;
    bf16x8 bf[2][4];
    #pragma unroll
    for (int ct=0;ct<2;ct++)
      #pragma unroll
      for (int s=0;s<4;s++)
        bf[ct][s] = *(const bf16x8*)(Wg + (cb+ct*16+lq)*128 + s*32 + lg*8);
    #pragma unroll
    for (int ct=0;ct<2;ct++)
      #pragma unroll
      for (int s=0;s<4;s++)
        acc[ct] = __builtin_amdgcn_mfma_f32_16x16x32_bf16(af[s], bf[ct][s], acc[ct], 0,0,0);
  }
  // epilogue1: res = c + bo + deg + x   (keep in regs + LDS for LN)
  const float* xres = (row0<4096)? (xa + row0*128) : (xb + (row0-4096)*128);
  float rv[2][4];
  #pragma unroll
  for (int ct=0;ct<2;ct++){
    int col = cb + ct*16 + lq;
    float bb = bo[col];
    #pragma unroll
    for (int r=0;r<4;r++){
      int lr = 4*lg + r;
      rv[ct][r] = acc[ct][r] + bb + deg[row0+lr] + xres[lr*128 + col];
      rs[lr][col] = rv[ct][r];
    }
  }
  __syncthreads();
  { // LN(gf1) then LN(gf2), 16 thr/row; write bf16 swizzled into abf
    int r = t>>4, c0 = t&15;
    float s=0.f, s2=0.f;
    #pragma unroll
    for (int j=0;j<8;j++){ float v = rs[r][c0+j*16]; s+=v; s2+=v*v; }
    #pragma unroll
    for (int m=1;m<16;m<<=1){ s += __shfl_xor(s,m); s2 += __shfl_xor(s2,m); }
    float mean = s*0.0078125f;
    float var  = s2*0.0078125f - mean*mean;
    float rstd = rsqrtf(var + 1e-5f);
    float h8[8];
    #pragma unroll
    for (int j=0;j<8;j++){ int c=c0+j*16; h8[j] = (rs[r][c]-mean)*rstd*gf1[c] + bf1[c]; }
    s=0.f; s2=0.f;
    #pragma unroll
    for (int j=0;j<8;j++){ s+=h8[j]; s2+=h8[j]*h8[j]; }
    #pragma unroll
    for (int m=1;m<16;m<<=1){ s += __shfl_xor(s,m); s2 += __shfl_xor(s2,m); }
    float mean2 = s*0.0078125f;
    float var2  = s2*0.0078125f - mean2*mean2;
    float rstd2 = rsqrtf(var2 + 1e-5f);
    #pragma unroll
    for (int j=0;j<8;j++){
      int c = c0 + j*16;
      float h = (h8[j]-mean2)*rstd2*gf2[c] + bf2[c];
      int sj = (c>>3) ^ (r&7);
      abf[r][sj*8 + (c&7)] = f2bf(h);
    }
  }
  __syncthreads();
  // GEMM2: @W1 -> gelu
  #pragma unroll
  for (int s=0;s<4;s++){ int sj = (s*4+lg) ^ (lq&7); af[s] = *(const bf16x8*)&abf[lq][sj*8]; }
  acc[0] = (f32x4){0,0,0,0}; acc[1] = (f32x4){0,0,0,0};
  {
    const u16* Wg = WT + 4*16384;
    bf16x8 bf[2][4];
    #pragma unroll
    for (int ct=0;ct<2;ct++)
      #pragma unroll
      for (int s=0;s<4;s++)
        bf[ct][s] = *(const bf16x8*)(Wg + (cb+ct*16+lq)*128 + s*32 + lg*8);
    #pragma unroll
    for (int ct=0;ct<2;ct++)
      #pragma unroll
      for (int s=0;s<4;s++)
        acc[ct] = __builtin_amdgcn_mfma_f32_16x16x32_bf16(af[s], bf[ct][s], acc[ct], 0,0,0);
  }
  float gvv[2][4];
  #pragma unroll
  for (int ct=0;ct<2;ct++){
    int col = cb + ct*16 + lq;
    float bb = b1[col];
    #pragma unroll
    for (int r=0;r<4;r++){
      float v = acc[ct][r] + bb;
      gvv[ct][r] = 0.5f*v*(1.f + erff(v*0.70710678118654752f));
    }
  }
  __syncthreads();   // all GEMM2 A-reads done before overwrite
  #pragma unroll
  for (int ct=0;ct<2;ct++){
    int col = cb + ct*16 + lq;
    #pragma unroll
    for (int r=0;r<4;r++){
      int lr = 4*lg + r;
      int sj = (col>>3) ^ (lr&7);
      abf[lr][sj*8 + (col&7)] = f2bf(gvv[ct][r]);
    }
  }
  __syncthreads();
  // GEMM3: @W2 + b2 + res -> out
  #pragma unroll
  for (int s=0;s<4;s++){ int sj = (s*4+lg) ^ (lq&7); af[s] = *(const bf16x8*)&abf[lq][sj*8]; }
  acc[0] = (f32x4){0,0,0,0}; acc[1] = (f32x4){0,0,0,0};
  {
    const u16* Wg = WT + 5*16384;
    bf16x8 bf[2][4];
    #pragma unroll
    for (int ct=0;ct<2;ct++)
      #pragma unroll
      for (int s=0;s<4;s++)
        bf[ct][s] = *(const bf16x8*)(Wg + (cb+ct*16+lq)*128 + s*32 + lg*8);
    #pragma unroll
    for (int ct=0;ct<2;ct++)
      #pragma unroll
      for (int s=0;s<4;s++)
        acc[ct] = __builtin_amdgcn_mfma_f32_16x16x32_bf16(af[s], bf[ct][s], acc[ct], 0,0,0);
  }
  #pragma unroll
  for (int ct=0;ct<2;ct++){
    int col = cb + ct*16 + lq;
    float bb = b2[col];
    #pragma unroll
    for (int r=0;r<4;r++){
      int lr = 4*lg + r;
      out[(row0+lr)*128 + col] = acc[ct][r] + bb + rv[ct][r];
    }
  }
}

extern "C" void kernel_launch(void* const* d_in, const int* in_sizes, int n_in,
                              void* d_out, int out_size, void* d_ws, size_t ws_size,
                              hipStream_t stream) {
  const float* xa  = (const float*)d_in[0];
  const float* xb  = (const float*)d_in[1];
  const int*   eab = (const int*)d_in[2];
  const int*   eba = (const int*)d_in[3];
  const float* Wq  = (const float*)d_in[4];   const float* bq = (const float*)d_in[5];
  const float* Wk  = (const float*)d_in[6];   const float* bk = (const float*)d_in[7];
  const float* Wv  = (const float*)d_in[8];   const float* bv = (const float*)d_in[9];
  const float* Wo  = (const float*)d_in[10];  const float* bo = (const float*)d_in[11];
  const float* ga  = (const float*)d_in[12];  const float* ba = (const float*)d_in[13];
  const float* gfn = (const float*)d_in[14];  const float* bfn= (const float*)d_in[15];
  const float* gf  = (const float*)d_in[16];  const float* bf = (const float*)d_in[17];
  const float* W1  = (const float*)d_in[18];  const float* b1 = (const float*)d_in[19];
  const float* W2  = (const float*)d_in[20];  const float* b2 = (const float*)d_in[21];
  float* out = (float*)d_out;

  // ws: deg 32KB | WT 192KB | Qb,Kb,VT 2MB each | attnraw 4MB  (~10.5MB)
  char* w = (char*)d_ws;
  float* deg     = (float*)w;
  u16*   WT      = (u16*)(w + 32768);
  u16*   Qb      = (u16*)(w + 32768 + 196608);
  u16*   Kb      = Qb + NEL;
  u16*   VT      = Kb + NEL;
  float* attnraw = (float*)(VT + NEL);

  hipMemsetAsync(deg, 0, 8192*sizeof(float), stream);
  prep_kernel<<<352, 256, 0, stream>>>(eab, eba, deg, Wq, Wk, Wv, Wo, W1, W2, WT);
  ln_qkv_kernel<<<512, 256, 0, stream>>>(xa, xb, ga, ba, WT, bq, bk, bv, Qb, Kb, VT);
  attn_kernel<<<dim3(64,4,2), 256, 0, stream>>>(Qb, Kb, VT, attnraw);
  tail_kernel<<<512, 256, 0, stream>>>(attnraw, WT, bo, deg, xa, xb,
                                       gfn, bfn, gf, bf, b1, b2, out);
}

// Round 4
// 184.253 us; speedup vs baseline: 1.6388x; 1.0599x over previous
//
#include <hip/hip_runtime.h>

typedef unsigned short u16;
typedef unsigned int   u32;
typedef __attribute__((ext_vector_type(8))) short bf16x8;  // 8 bf16 (4 VGPRs)
typedef __attribute__((ext_vector_type(4))) float f32x4;   // MFMA acc

#define NEL (8192*128)

// async global->LDS, 16B per lane, LDS dest = wave-uniform base + lane*16
#define ASYNC16(ldsptr, gptr) __builtin_amdgcn_global_load_lds( \
    (const __attribute__((address_space(1))) u32*)(gptr), \
    (__attribute__((address_space(3))) u32*)(ldsptr), 16, 0, 0)

__device__ __forceinline__ u16 f2bf(float f){
  u32 u = __builtin_bit_cast(u32, f);
  u = (u + 0x7FFFu + ((u >> 16) & 1u)) >> 16;  // RNE
  return (u16)u;
}
__device__ __forceinline__ u32 pk2(float a, float b){  // lo=bf16(a), hi=bf16(b)
  u32 r;
  asm("v_cvt_pk_bf16_f32 %0, %1, %2" : "=v"(r) : "v"(a), "v"(b));
  return r;
}

// ---------------- prep: degree atomics (blocks 0..255) + weight bf16 transpose (256..351) ----------------
// WT layout: [6][128][128] bf16, WT[w][n][k] = W_w[k][n]  (k-contiguous for B-frags)
__global__ __launch_bounds__(256) void prep_kernel(
    const int* __restrict__ eab, const int* __restrict__ eba, float* __restrict__ deg,
    const float* __restrict__ Wq, const float* __restrict__ Wk, const float* __restrict__ Wv,
    const float* __restrict__ Wo, const float* __restrict__ W1, const float* __restrict__ W2,
    u16* __restrict__ WT)
{
  __shared__ float tile[32][33];
  const int b = blockIdx.x, t = threadIdx.x;
  if (b < 256){
    int e = b*256 + t;
    atomicAdd(&deg[eab[e]],              1.f);
    atomicAdd(&deg[4096 + eab[65536+e]], 1.f);
    atomicAdd(&deg[4096 + eba[e]],       1.f);
    atomicAdd(&deg[eba[65536+e]],        1.f);
  } else {
    int id = b - 256;                 // 0..95 = 6 W x 16 tiles(32x32)
    int w = id >> 4, tt = id & 15, tr = tt >> 2, tc = tt & 3;
    const float* W = (w==0)?Wq:(w==1)?Wk:(w==2)?Wv:(w==3)?Wo:(w==4)?W1:W2;
    int r = t >> 3, c4 = (t&7)*4;
    float4 v = *(const float4*)(W + (tr*32 + r)*128 + tc*32 + c4);
    tile[r][c4]=v.x; tile[r][c4+1]=v.y; tile[r][c4+2]=v.z; tile[r][c4+3]=v.w;
    __syncthreads();
    int n = t >> 3, k4 = (t&7)*4;     // write WT[w][tc*32+n][tr*32+k4..+3]
    u32 lo = pk2(tile[k4+0][n], tile[k4+1][n]);
    u32 hi = pk2(tile[k4+2][n], tile[k4+3][n]);
    *(uint2*)(WT + w*16384 + (tc*32+n)*128 + tr*32 + k4) = make_uint2(lo, hi);
  }
}

// ---------------- LN(x); MFMA x@{Wq,Wk,Wv}+b -> bf16 Q(pre-scaled),K,V^T ----------------
// 512 blocks x 512 thr (8 waves), 16 rows/block; wave w -> cols 16w..16w+15
__global__ __launch_bounds__(512) void ln_qkv_kernel(
    const float* __restrict__ xa, const float* __restrict__ xb,
    const float* __restrict__ g, const float* __restrict__ bvec,
    const u16* __restrict__ WT,
    const float* __restrict__ bq, const float* __restrict__ bk, const float* __restrict__ bv,
    u16* __restrict__ Qb, u16* __restrict__ Kb, u16* __restrict__ VT)
{
  __shared__ float xs[16][132];
  __shared__ __align__(16) u16 abf[16][128];   // bf16 A-tile, 16B chunks XOR-swizzled
  __shared__ __align__(16) u16 vtb[128][24];   // V^T bounce (stride 48B)
  const int t = threadIdx.x, lane = t&63, wave = t>>6;
  const int lq = lane&15, lg = lane>>4;
  const int row0 = blockIdx.x*16;
  const float* x = (row0 < 4096) ? (xa + row0*128) : (xb + (row0-4096)*128);
  { // stage 16x128 f32: one float4/thread
    int r = t>>5, c4 = (t&31)*4;
    float4 v = *(const float4*)(x + r*128 + c4);
    xs[r][c4]=v.x; xs[r][c4+1]=v.y; xs[r][c4+2]=v.z; xs[r][c4+3]=v.w;
  }
  __syncthreads();
  if (t < 256){ // LN, 16 threads/row; write bf16 swizzled A-tile
    int r = t>>4, c0 = t&15;
    float s=0.f, s2=0.f;
    #pragma unroll
    for (int j=0;j<8;j++){ float v = xs[r][c0+j*16]; s+=v; s2+=v*v; }
    #pragma unroll
    for (int m=1;m<16;m<<=1){ s += __shfl_xor(s,m); s2 += __shfl_xor(s2,m); }
    float mean = s*0.0078125f;
    float var  = s2*0.0078125f - mean*mean;
    float rstd = rsqrtf(var + 1e-5f);
    #pragma unroll
    for (int j=0;j<8;j++){
      int c = c0 + j*16;
      float h = (xs[r][c]-mean)*rstd*g[c] + bvec[c];
      int sj = (c>>3) ^ (r&7);
      abf[r][sj*8 + (c&7)] = f2bf(h);
    }
  }
  __syncthreads();
  // A-frags: row=lq, k=s*32+lg*8
  bf16x8 af[4];
  #pragma unroll
  for (int s=0;s<4;s++){
    int sj = (s*4+lg) ^ (lq&7);
    af[s] = *(const bf16x8*)&abf[lq][sj*8];
  }
  const int cb = wave*16;
  const float QSC = 0.17677669529663687f * 1.4426950408889634f; // 1/sqrt(32)*log2e
  #pragma unroll
  for (int m=0;m<3;m++){
    const u16* Wg = WT + m*16384;
    bf16x8 bfr[4];
    #pragma unroll
    for (int s=0;s<4;s++)
      bfr[s] = *(const bf16x8*)(Wg + (cb+lq)*128 + s*32 + lg*8);
    f32x4 acc = {0,0,0,0};
    #pragma unroll
    for (int s=0;s<4;s++)
      acc = __builtin_amdgcn_mfma_f32_16x16x32_bf16(af[s], bfr[s], acc, 0,0,0);
    int col = cb + lq;
    if (m==0){
      float bb = bq[col];
      #pragma unroll
      for (int r=0;r<4;r++)
        Qb[(row0+4*lg+r)*128 + col] = f2bf((acc[r]+bb)*QSC);
    } else if (m==1){
      float bb = bk[col];
      #pragma unroll
      for (int r=0;r<4;r++)
        Kb[(row0+4*lg+r)*128 + col] = f2bf(acc[r]+bb);
    } else {
      float bb = bv[col];
      #pragma unroll
      for (int r=0;r<4;r++)
        vtb[col][4*lg+r] = f2bf(acc[r]+bb);
    }
  }
  __syncthreads();
  if (t < 256){ // V^T global write: c = t>>1, half = t&1 (16B each)
    int c = t>>1, half = t&1;
    bf16x8 v = *(const bf16x8*)&vtb[c][half*8];
    *(bf16x8*)(VT + c*8192 + row0 + half*8) = v;
  }
}

// ---------------- flash attention: per-head, KV-split x4, m==0 softmax ----------------
// grid (64, 4 heads, 8 = dir*4+split); block 256 = 4 waves x 16 q; KBLK=64, 16 tiles.
// Partials (unnormalized num + den) -> combine in tail. K LDS src pre-swizzled
// cc=j^((key>>1)&3); V/P swizzle ^(row&7). 24KB LDS -> 6 blocks/CU.
__global__ __launch_bounds__(256) void attn_kernel(
    const u16* __restrict__ Qb, const u16* __restrict__ Kb,
    const u16* __restrict__ VT, float* __restrict__ numb, float* __restrict__ denb)
{
  __shared__ __align__(16) u16 Klds[2][2048];   // 64 keys x 4 chunks
  __shared__ __align__(16) u16 Vlds[2][2048];   // 32 d x 8 chunks
  __shared__ __align__(16) u16 Plds[4][1024];   // per wave: 16 q x 8 chunks
  const int t = threadIdx.x, wave = t>>6, lane = t&63;
  const int lq = lane&15, lg = lane>>4;
  const int h = blockIdx.y;
  const int dir = blockIdx.z >> 2, sp = blockIdx.z & 3;
  const int q = blockIdx.x*64 + wave*16 + lq + (dir ? 4096 : 0);
  const int kvb = (dir ? 0 : 4096) + sp*1024;

  bf16x8 qf = *(const bf16x8*)(Qb + q*128 + h*32 + lg*8);
  f32x4 acc0 = {0,0,0,0}, acc1 = {0,0,0,0}, accL = {0,0,0,0};
  bf16x8 ones;
  #pragma unroll
  for (int i=0;i<8;i++) ones[i] = (short)0x3F80;

  // staging sources: K thread t -> key=t>>2, chunk j=t&3, src cc = j ^ ((key>>1)&3)
  //                  V thread t -> d=t>>3, chunk j=t&7,  src cc = j ^ (d&7)
  const u16* gk = Kb + (kvb + (t>>2))*128 + h*32 + ((t&3) ^ ((t>>3)&3))*8;
  const u16* gv = VT + (h*32 + (t>>3))*8192 + kvb + ((t&7) ^ ((t>>3)&7))*8;

  ASYNC16(&Klds[0][t*8], gk);
  ASYNC16(&Vlds[0][t*8], gv);
  asm volatile("s_waitcnt vmcnt(0)" ::: "memory");
  __builtin_amdgcn_s_barrier();

  int cur = 0;
  for (int kt=0; kt<16; ++kt){
    if (kt < 15){
      gk += 8192; gv += 64;
      ASYNC16(&Klds[cur^1][t*8], gk);
      ASYNC16(&Vlds[cur^1][t*8], gv);
    }
    const u16* KL = Klds[cur];
    const u16* VL = Vlds[cur];
    u16* PL = Plds[wave] + lq*64;
    // S^T (4 MFMA) -> exp2 -> pack -> P LDS
    const int ksj = lg ^ ((lq>>1)&3);
    #pragma unroll
    for (int f=0; f<4; ++f){
      bf16x8 kf = *(const bf16x8*)(KL + (f*16+lq)*32 + ksj*8);
      f32x4 st = __builtin_amdgcn_mfma_f32_16x16x32_bf16(kf, qf, (f32x4){0.f,0.f,0.f,0.f}, 0,0,0);
      float p0 = __builtin_amdgcn_exp2f(st[0]);
      float p1 = __builtin_amdgcn_exp2f(st[1]);
      float p2 = __builtin_amdgcn_exp2f(st[2]);
      float p3 = __builtin_amdgcn_exp2f(st[3]);
      int j = f*2 + (lg>>1);
      *(uint2*)(PL + ((j ^ (lq&7))<<3) + (lg&1)*4) = make_uint2(pk2(p0,p1), pk2(p2,p3));
    }
    // PV + l-sum: 6 MFMA
    #pragma unroll
    for (int kc=0; kc<2; ++kc){
      int sj = (kc*4+lg) ^ (lq&7);
      bf16x8 pf  = *(const bf16x8*)(PL + (sj<<3));
      bf16x8 vf0 = *(const bf16x8*)(VL + lq*64      + (sj<<3));
      bf16x8 vf1 = *(const bf16x8*)(VL + (16+lq)*64 + (sj<<3));
      acc0 = __builtin_amdgcn_mfma_f32_16x16x32_bf16(vf0,  pf, acc0, 0,0,0);
      acc1 = __builtin_amdgcn_mfma_f32_16x16x32_bf16(vf1,  pf, acc1, 0,0,0);
      accL = __builtin_amdgcn_mfma_f32_16x16x32_bf16(ones, pf, accL, 0,0,0);
    }
    asm volatile("s_waitcnt vmcnt(0)" ::: "memory");
    __builtin_amdgcn_s_barrier();
    cur ^= 1;
  }
  float* outp = numb + sp*NEL + q*128 + h*32 + 4*lg;   // d = h*32 + 4lg + r
  *(float4*)(outp)      = make_float4(acc0[0], acc0[1], acc0[2], acc0[3]);
  *(float4*)(outp + 16) = make_float4(acc1[0], acc1[1], acc1[2], acc1[3]);
  if (lg == 0) denb[sp*32768 + q*4 + h] = accL[0];
}

// ---------------- MFMA tail: combine splits; @Wo+bo+deg+x -> res ; LN;LN ; @W1+gelu ; @W2+b2+res ----------------
// 512 blocks x 512 thr (8 waves), 16 rows; wave w -> cols 16w..+15
__global__ __launch_bounds__(512) void tail_kernel(
    const float* __restrict__ numb, const float* __restrict__ denb,
    const u16* __restrict__ WT,
    const float* __restrict__ bo, const float* __restrict__ deg,
    const float* __restrict__ xa, const float* __restrict__ xb,
    const float* __restrict__ gf1, const float* __restrict__ bf1,
    const float* __restrict__ gf2, const float* __restrict__ bf2,
    const float* __restrict__ b1, const float* __restrict__ b2,
    float* __restrict__ out)
{
  __shared__ __align__(16) u16 abf[16][128];
  __shared__ float rs[16][132];
  const int t = threadIdx.x, lane = t&63, wave = t>>6;
  const int lq = lane&15, lg = lane>>4;
  const int row0 = blockIdx.x*16;
  const int cb = wave*16;

  { // combine 4 KV-split partials, normalize, -> bf16 swizzled A-tile
    int r = t>>5, c0 = (t&31)*4, hh = c0>>5;
    const float* np = numb + (row0+r)*128 + c0;
    float4 s0 = *(const float4*)(np);
    float4 s1 = *(const float4*)(np + NEL);
    float4 s2 = *(const float4*)(np + 2*NEL);
    float4 s3 = *(const float4*)(np + 3*NEL);
    int di = (row0+r)*4 + hh;
    float den = denb[di] + denb[32768+di] + denb[65536+di] + denb[98304+di];
    float inv = 1.0f/den;
    float a0 = (s0.x+s1.x+s2.x+s3.x)*inv;
    float a1 = (s0.y+s1.y+s2.y+s3.y)*inv;
    float a2 = (s0.z+s1.z+s2.z+s3.z)*inv;
    float a3 = (s0.w+s1.w+s2.w+s3.w)*inv;
    int sj = (c0>>3) ^ (r&7);
    *(uint2*)&abf[r][sj*8 + (c0&7)] = make_uint2(pk2(a0,a1), pk2(a2,a3));
  }
  __syncthreads();

  bf16x8 af[4];
  #pragma unroll
  for (int s=0;s<4;s++){ int sj = (s*4+lg) ^ (lq&7); af[s] = *(const bf16x8*)&abf[lq][sj*8]; }

  // GEMM1: @Wo
  f32x4 acc = {0,0,0,0};
  {
    const u16* Wg = WT + 3*16384;
    bf16x8 bfr[4];
    #pragma unroll
    for (int s=0;s<4;s++) bfr[s] = *(const bf16x8*)(Wg + (cb+lq)*128 + s*32 + lg*8);
    #pragma unroll
    for (int s=0;s<4;s++) acc = __builtin_amdgcn_mfma_f32_16x16x32_bf16(af[s], bfr[s], acc, 0,0,0);
  }
  // epilogue1: res = c + bo + deg + x
  const float* xres = (row0<4096)? (xa + row0*128) : (xb + (row0-4096)*128);
  const int col = cb + lq;
  float rv[4];
  {
    float bb = bo[col];
    #pragma unroll
    for (int r=0;r<4;r++){
      int lr = 4*lg + r;
      rv[r] = acc[r] + bb + deg[row0+lr] + xres[lr*128 + col];
      rs[lr][col] = rv[r];
    }
  }
  __syncthreads();
  if (t < 256){ // LN(gf1) then LN(gf2); write bf16 swizzled into abf
    int r = t>>4, c0 = t&15;
    float s=0.f, s2=0.f;
    #pragma unroll
    for (int j=0;j<8;j++){ float v = rs[r][c0+j*16]; s+=v; s2+=v*v; }
    #pragma unroll
    for (int m=1;m<16;m<<=1){ s += __shfl_xor(s,m); s2 += __shfl_xor(s2,m); }
    float mean = s*0.0078125f;
    float var  = s2*0.0078125f - mean*mean;
    float rstd = rsqrtf(var + 1e-5f);
    float h8[8];
    #pragma unroll
    for (int j=0;j<8;j++){ int c=c0+j*16; h8[j] = (rs[r][c]-mean)*rstd*gf1[c] + bf1[c]; }
    s=0.f; s2=0.f;
    #pragma unroll
    for (int j=0;j<8;j++){ s+=h8[j]; s2+=h8[j]*h8[j]; }
    #pragma unroll
    for (int m=1;m<16;m<<=1){ s += __shfl_xor(s,m); s2 += __shfl_xor(s2,m); }
    float mean2 = s*0.0078125f;
    float var2  = s2*0.0078125f - mean2*mean2;
    float rstd2 = rsqrtf(var2 + 1e-5f);
    #pragma unroll
    for (int j=0;j<8;j++){
      int c = c0 + j*16;
      float h = (h8[j]-mean2)*rstd2*gf2[c] + bf2[c];
      int sj = (c>>3) ^ (r&7);
      abf[r][sj*8 + (c&7)] = f2bf(h);
    }
  }
  __syncthreads();
  // GEMM2: @W1 -> gelu
  #pragma unroll
  for (int s=0;s<4;s++){ int sj = (s*4+lg) ^ (lq&7); af[s] = *(const bf16x8*)&abf[lq][sj*8]; }
  acc = (f32x4){0,0,0,0};
  {
    const u16* Wg = WT + 4*16384;
    bf16x8 bfr[4];
    #pragma unroll
    for (int s=0;s<4;s++) bfr[s] = *(const bf16x8*)(Wg + (cb+lq)*128 + s*32 + lg*8);
    #pragma unroll
    for (int s=0;s<4;s++) acc = __builtin_amdgcn_mfma_f32_16x16x32_bf16(af[s], bfr[s], acc, 0,0,0);
  }
  float gvv[4];
  {
    float bb = b1[col];
    #pragma unroll
    for (int r=0;r<4;r++){
      float v = acc[r] + bb;
      gvv[r] = 0.5f*v*(1.f + erff(v*0.70710678118654752f));
    }
  }
  __syncthreads();   // all GEMM2 A-reads done before overwrite
  #pragma unroll
  for (int r=0;r<4;r++){
    int lr = 4*lg + r;
    int sj = (col>>3) ^ (lr&7);
    abf[lr][sj*8 + (col&7)] = f2bf(gvv[r]);
  }
  __syncthreads();
  // GEMM3: @W2 + b2 + res -> out
  #pragma unroll
  for (int s=0;s<4;s++){ int sj = (s*4+lg) ^ (lq&7); af[s] = *(const bf16x8*)&abf[lq][sj*8]; }
  acc = (f32x4){0,0,0,0};
  {
    const u16* Wg = WT + 5*16384;
    bf16x8 bfr[4];
    #pragma unroll
    for (int s=0;s<4;s++) bfr[s] = *(const bf16x8*)(Wg + (cb+lq)*128 + s*32 + lg*8);
    #pragma unroll
    for (int s=0;s<4;s++) acc = __builtin_amdgcn_mfma_f32_16x16x32_bf16(af[s], bfr[s], acc, 0,0,0);
  }
  {
    float bb = b2[col];
    #pragma unroll
    for (int r=0;r<4;r++){
      int lr = 4*lg + r;
      out[(row0+lr)*128 + col] = acc[r] + bb + rv[r];
    }
  }
}

extern "C" void kernel_launch(void* const* d_in, const int* in_sizes, int n_in,
                              void* d_out, int out_size, void* d_ws, size_t ws_size,
                              hipStream_t stream) {
  const float* xa  = (const float*)d_in[0];
  const float* xb  = (const float*)d_in[1];
  const int*   eab = (const int*)d_in[2];
  const int*   eba = (const int*)d_in[3];
  const float* Wq  = (const float*)d_in[4];   const float* bq = (const float*)d_in[5];
  const float* Wk  = (const float*)d_in[6];   const float* bk = (const float*)d_in[7];
  const float* Wv  = (const float*)d_in[8];   const float* bv = (const float*)d_in[9];
  const float* Wo  = (const float*)d_in[10];  const float* bo = (const float*)d_in[11];
  const float* ga  = (const float*)d_in[12];  const float* ba = (const float*)d_in[13];
  const float* gfn = (const float*)d_in[14];  const float* bfn= (const float*)d_in[15];
  const float* gf  = (const float*)d_in[16];  const float* bf = (const float*)d_in[17];
  const float* W1  = (const float*)d_in[18];  const float* b1 = (const float*)d_in[19];
  const float* W2  = (const float*)d_in[20];  const float* b2 = (const float*)d_in[21];
  float* out = (float*)d_out;

  // ws: deg 32KB | WT 192KB | Qb,Kb,VT 2MB each | num 16MB | den 512KB  (~23MB)
  char* w = (char*)d_ws;
  float* deg  = (float*)w;
  u16*   WT   = (u16*)(w + 32768);
  u16*   Qb   = (u16*)(w + 32768 + 196608);
  u16*   Kb   = Qb + NEL;
  u16*   VT   = Kb + NEL;
  float* numb = (float*)(VT + NEL);
  float* denb = numb + 4*NEL;

  hipMemsetAsync(deg, 0, 8192*sizeof(float), stream);
  prep_kernel<<<352, 256, 0, stream>>>(eab, eba, deg, Wq, Wk, Wv, Wo, W1, W2, WT);
  ln_qkv_kernel<<<512, 512, 0, stream>>>(xa, xb, ga, ba, WT, bq, bk, bv, Qb, Kb, VT);
  attn_kernel<<<dim3(64,4,8), 256, 0, stream>>>(Qb, Kb, VT, numb, denb);
  tail_kernel<<<512, 512, 0, stream>>>(numb, denb, WT, bo, deg, xa, xb,
                                       gfn, bfn, gf, bf, b1, b2, out);
}